// Round 3
// baseline (1535.570 us; speedup 1.0000x reference)
//
#include <hip/hip_runtime.h>
#include <hip/hip_bf16.h>

#define NN 100000
#define DD 64
#define NE 1600000
#define ND (NN*DD)
#define EPSLN 1e-3f

typedef __hip_bfloat16 bf16;
__device__ __forceinline__ float b2f(bf16 x){ return __bfloat162float(x); }

// ---- pf (f32 param) sublayout ----
#define PF_EMBA 0
#define PF_EMBB 64
#define PF_WAB  128
#define PF_BAB  8320
#define PF_WBA  8448
#define PF_BBA  16640
#define PF_BTA  16768
#define PF_BTB  16896
#define PF_TOT  17024

// ---- ws layout (4-byte units) ----
// hist[4N] | cur[2N] | rs[4N] | offAB[N+pad] | offBA[N+pad] | pf | v | flag | csrAB[NE] | csrBA[NE] | hsA,hsB (bf16)
#define WS_HIST   0
#define WS_CUR    (4*NN)
#define WS_RS     (6*NN)
#define WS_OFFAB  (10*NN)
#define WS_OFFBA  (11*NN + 16)
#define WS_PF     (12*NN + 32)
#define WS_V      (WS_PF + PF_TOT)
#define WS_FLAG   (WS_V + 128)
#define WS_CSRAB  (13*NN)          // 1,300,000 > WS_FLAG+pad (~1,217,190)
#define WS_CSRBA  (WS_CSRAB + NE)
#define WS_HS     (WS_CSRBA + NE)  // bf16 region starts here (byte off = WS_HS*4)

// 64-lane LayerNorm
__device__ __forceinline__ float wave_ln(float x, float beta){
  float s = x, s2 = x*x;
  #pragma unroll
  for (int off = 32; off >= 1; off >>= 1){
    s  += __shfl_xor(s,  off);
    s2 += __shfl_xor(s2, off);
  }
  float mu  = s  * (1.0f/DD);
  float var = s2 * (1.0f/DD) - mu*mu;
  return (x - mu) * rsqrtf(var + EPSLN) + beta;
}

// dtype sniff on W_ab bits (bf16 exponents cluster in [110,130]; f32-as-u16 doesn't)
__global__ void k_detect(const unsigned short* __restrict__ w, int* __restrict__ flag){
  int lane = threadIdx.x;
  int bad = 0;
  for (int i = lane; i < 4096; i += 64){
    int e = (w[i] >> 7) & 0xFF;
    if (e < 110 || e > 130) bad++;
  }
  #pragma unroll
  for (int off = 32; off >= 1; off >>= 1) bad += __shfl_xor(bad, off);
  if (lane == 0) *flag = (bad > 500) ? 1 : 0;   // 1 = f32, 0 = bf16
}

__global__ void k_convert(const void* embA, const void* embB, const void* Wab, const void* bab,
                          const void* Wba, const void* bba, const void* betaA, const void* betaB,
                          const int* __restrict__ flag, float* __restrict__ pf){
  int i = blockIdx.x*blockDim.x + threadIdx.x;
  if (i >= PF_TOT) return;
  int f32 = *flag;
  const void* src; int j;
  if      (i < PF_EMBB) { src=embA;  j=i; }
  else if (i < PF_WAB)  { src=embB;  j=i-PF_EMBB; }
  else if (i < PF_BAB)  { src=Wab;   j=i-PF_WAB; }
  else if (i < PF_WBA)  { src=bab;   j=i-PF_BAB; }
  else if (i < PF_BBA)  { src=Wba;   j=i-PF_WBA; }
  else if (i < PF_BTA)  { src=bba;   j=i-PF_BBA; }
  else if (i < PF_BTB)  { src=betaA; j=i-PF_BTA; }
  else                  { src=betaB; j=i-PF_BTB; }
  pf[i] = f32 ? ((const float*)src)[j] : b2f(((const bf16*)src)[j]);
}

// hist: [0,N) cnt(sab)  [N,2N) cnt(dab)  [2N,3N) cnt(sba)  [3N,4N) cnt(dba)
__global__ void k_hist(const int* __restrict__ sab, const int* __restrict__ dab,
                       const int* __restrict__ sba, const int* __restrict__ dba,
                       int* __restrict__ hist){
  int e = blockIdx.x*blockDim.x + threadIdx.x;
  if (e >= NE) return;
  atomicAdd(&hist[sab[e]], 1);
  atomicAdd(&hist[NN + dab[e]], 1);
  atomicAdd(&hist[2*NN + sba[e]], 1);
  atomicAdd(&hist[3*NN + dba[e]], 1);
}

__global__ void k_rs(const int* __restrict__ hist, float* __restrict__ rs){
  int i = blockIdx.x*blockDim.x + threadIdx.x;
  if (i >= 4*NN) return;
  rs[i] = rsqrtf((float)max(hist[i], 1));
}

// exclusive scan of in-degree counts -> CSR row offsets. block 0: AB (dab), block 1: BA (dba)
__global__ void k_scan(const int* __restrict__ hist, int* __restrict__ offAB, int* __restrict__ offBA){
  __shared__ int lds[1024];
  __shared__ int sbase;
  const int* c = (blockIdx.x == 0) ? (hist + NN) : (hist + 3*NN);
  int* o       = (blockIdx.x == 0) ? offAB : offBA;
  if (threadIdx.x == 0) sbase = 0;
  __syncthreads();
  for (int start = 0; start < NN; start += 1024){
    int i = start + (int)threadIdx.x;
    int x = (i < NN) ? c[i] : 0;
    lds[threadIdx.x] = x;
    __syncthreads();
    for (int d = 1; d < 1024; d <<= 1){
      int t = (threadIdx.x >= (unsigned)d) ? lds[threadIdx.x - d] : 0;
      __syncthreads();
      lds[threadIdx.x] += t;
      __syncthreads();
    }
    int incl = lds[threadIdx.x];
    int b = sbase;
    __syncthreads();
    if (i < NN) o[i] = b + incl - x;
    if (threadIdx.x == 1023) sbase = b + lds[1023];
    __syncthreads();
  }
  if (threadIdx.x == 0) o[NN] = sbase;
}

// scatter edge srcs into per-dst buckets via atomic cursors
__global__ void k_bucket(const int* __restrict__ sab, const int* __restrict__ dab,
                         const int* __restrict__ sba, const int* __restrict__ dba,
                         const int* __restrict__ offAB, const int* __restrict__ offBA,
                         int* __restrict__ cur, int* __restrict__ csrAB, int* __restrict__ csrBA){
  int e = blockIdx.x*blockDim.x + threadIdx.x;
  if (e >= 2*NE) return;
  if (e < NE){
    int d = dab[e];
    int pos = atomicAdd(&cur[d], 1);
    csrAB[offAB[d] + pos] = sab[e];
  } else {
    int ee = e - NE;
    int d = dba[ee];
    int pos = atomicAdd(&cur[NN + d], 1);
    csrBA[offBA[d] + pos] = sba[ee];
  }
}

// vAB = embA @ Wab[0], vBA = embB @ Wba[0]
__global__ void k_matvec(const float* __restrict__ pf, float* __restrict__ v){
  int t = threadIdx.x;           // 128 threads
  int d = t & (DD-1);
  const float* emb = pf + ((t < DD) ? PF_EMBA : PF_EMBB);
  const float* W   = pf + ((t < DD) ? PF_WAB  : PF_WBA);
  float acc = 0.f;
  for (int k = 0; k < DD; k++) acc += emb[k] * W[k*DD + d];
  v[(t < DD) ? d : (DD + d)] = acc;
}

// layer-0: wave per node (CSR gather of scalar coefs, zero atomics).
// writes h -> d_out (flag dtype) and hs = bf16(h * rs_out) -> ws
__global__ void k_layer0(const int* __restrict__ csrAB, const int* __restrict__ csrBA,
                         const int* __restrict__ offAB, const int* __restrict__ offBA,
                         const float* __restrict__ rs, const float* __restrict__ v,
                         const float* __restrict__ pf, const int* __restrict__ flag,
                         void* __restrict__ out, bf16* __restrict__ hsA, bf16* __restrict__ hsB){
  int w = (blockIdx.x*blockDim.x + threadIdx.x) >> 6;
  int lane = threadIdx.x & 63;
  if (w >= 2*NN) return;
  int f32 = *flag;
  bool isA = (w < NN);
  int n = isA ? w : (w - NN);
  const int* csr; const int* off; int rsbase;
  float vd, bias, beta, e0, rin;
  if (isA){   // outA over ba edges
    csr = csrBA; off = offBA; rsbase = 2*NN; rin = rs[3*NN + n];
    vd = v[DD + lane]; bias = pf[PF_BBA + lane]; beta = pf[PF_BTA + lane]; e0 = pf[PF_EMBA + lane];
  } else {    // outB over ab edges
    csr = csrAB; off = offAB; rsbase = 0;    rin = rs[NN + n];
    vd = v[lane];      bias = pf[PF_BAB + lane]; beta = pf[PF_BTB + lane]; e0 = pf[PF_EMBB + lane];
  }
  int o0 = off[n], o1 = off[n+1];
  float c = 0.f;
  for (int t = o0 + lane; t < o1; t += 64) c += rs[rsbase + csr[t]];
  #pragma unroll
  for (int off2 = 32; off2 >= 1; off2 >>= 1) c += __shfl_xor(c, off2);
  float ov = fmaxf(c * rin * vd + bias, 0.f);
  float res = wave_ln(e0 + ov, beta);
  size_t idx = (size_t)w*DD + lane;
  if (f32) ((float*)out)[idx] = res;
  else     ((bf16*)out)[idx] = __float2bfloat16(res);
  float rscale = isA ? rs[n] : rs[2*NN + n];   // out-degree scale for this node as a SOURCE
  (isA ? hsA : hsB)[(size_t)n*DD + lane] = __float2bfloat16(res * rscale);
}

// layer-1 fused gather + matvec + LN. Block = 4 waves = 4 nodes (exact grid).
// acc row -> LDS -> wave-uniform float4 broadcast reads against per-lane W column.
__global__ __launch_bounds__(256) void k_gather_l1(
    const int* __restrict__ csr, const int* __restrict__ off,
    const bf16* __restrict__ hs, const float* __restrict__ rs_in,
    const float* __restrict__ W, const float* __restrict__ bias_,
    const float* __restrict__ beta_, const int* __restrict__ flag,
    void* __restrict__ out, size_t base){
  int lane = threadIdx.x & 63;
  int wid  = threadIdx.x >> 6;
  int n = blockIdx.x*4 + wid;          // grid = 25000 blocks -> n < 100000 always
  int f32 = *flag;
  float Wcol[DD];
  #pragma unroll
  for (int k = 0; k < DD; k++) Wcol[k] = W[k*DD + lane];
  float bs = bias_[lane];
  float bt = beta_[lane];
  int o0 = off[n], o1 = off[n+1];
  float acc = 0.f;
  for (int t = o0; t < o1; t++){       // wave-uniform t -> scalar csr load
    int s = csr[t];
    acc += b2f(hs[(size_t)s*DD + lane]);   // 128B coalesced row read
  }
  __shared__ __align__(16) float srow[4][DD];
  srow[wid][lane] = acc;
  __syncthreads();                     // block-uniform point
  const float4* ar = (const float4*)srow[wid];
  float o = 0.f;
  #pragma unroll
  for (int k4 = 0; k4 < DD/4; k4++){
    float4 a4 = ar[k4];                // wave-uniform LDS broadcast
    o += a4.x*Wcol[4*k4] + a4.y*Wcol[4*k4+1] + a4.z*Wcol[4*k4+2] + a4.w*Wcol[4*k4+3];
  }
  o = fmaxf(o * rs_in[n] + bs, 0.f);
  size_t idx = base + (size_t)n*DD + lane;
  float hv = f32 ? ((const float*)out)[idx] : b2f(((const bf16*)out)[idx]);
  float res = wave_ln(hv + o, bt);
  if (f32) ((float*)out)[idx] = res;
  else     ((bf16*)out)[idx] = __float2bfloat16(res);
}

extern "C" void kernel_launch(void* const* d_in, const int* in_sizes, int n_in,
                              void* d_out, int out_size, void* d_ws, size_t ws_size,
                              hipStream_t stream){
  const int* sab = (const int*)d_in[0];
  const int* dab = (const int*)d_in[1];
  const int* sba = (const int*)d_in[2];
  const int* dba = (const int*)d_in[3];

  int*   wsi   = (int*)d_ws;
  float* wsf   = (float*)d_ws;
  int*   hist  = wsi + WS_HIST;
  int*   cur   = wsi + WS_CUR;
  float* rs    = wsf + WS_RS;
  int*   offAB = wsi + WS_OFFAB;
  int*   offBA = wsi + WS_OFFBA;
  float* pf    = wsf + WS_PF;
  float* v     = wsf + WS_V;
  int*   flag  = wsi + WS_FLAG;
  int*   csrAB = wsi + WS_CSRAB;
  int*   csrBA = wsi + WS_CSRBA;
  bf16*  hsA   = (bf16*)(wsi + WS_HS);
  bf16*  hsB   = hsA + ND;

  // zero hist[4N] + cur[2N] (contiguous)
  hipMemsetAsync(d_ws, 0, (size_t)(6*NN)*sizeof(int), stream);

  k_detect <<<1, 64, 0, stream>>>((const unsigned short*)d_in[6], flag);
  k_convert<<<(PF_TOT+255)/256, 256, 0, stream>>>(d_in[4], d_in[5], d_in[6], d_in[7],
                                                  d_in[8], d_in[9], d_in[10], d_in[11],
                                                  flag, pf);
  k_hist   <<<(NE+255)/256, 256, 0, stream>>>(sab, dab, sba, dba, hist);
  k_rs     <<<(4*NN+255)/256, 256, 0, stream>>>(hist, rs);
  k_scan   <<<2, 1024, 0, stream>>>(hist, offAB, offBA);
  k_bucket <<<(2*NE+255)/256, 256, 0, stream>>>(sab, dab, sba, dba, offAB, offBA,
                                                cur, csrAB, csrBA);
  k_matvec <<<1, 128, 0, stream>>>(pf, v);
  k_layer0 <<<(2*NN)/4, 256, 0, stream>>>(csrAB, csrBA, offAB, offBA, rs, v, pf, flag,
                                          d_out, hsA, hsB);
  // A half: in-edges = ba relation, sources are B nodes
  k_gather_l1<<<NN/4, 256, 0, stream>>>(csrBA, offBA, hsB, rs + 3*NN,
                                        pf + PF_WBA + DD*DD, pf + PF_BBA + DD,
                                        pf + PF_BTA + DD, flag, d_out, 0);
  // B half: in-edges = ab relation, sources are A nodes
  k_gather_l1<<<NN/4, 256, 0, stream>>>(csrAB, offAB, hsA, rs + NN,
                                        pf + PF_WAB + DD*DD, pf + PF_BAB + DD,
                                        pf + PF_BTB + DD, flag, d_out, (size_t)ND);
}

// Round 5
// 1180.171 us; speedup vs baseline: 1.3011x; 1.3011x over previous
//
#include <hip/hip_runtime.h>
#include <hip/hip_bf16.h>

#define NN 100000
#define DD 64
#define NE 1600000
#define ND (NN*DD)
#define EPSLN 1e-3f

typedef __hip_bfloat16 bf16;
__device__ __forceinline__ float b2f(bf16 x){ return __bfloat162float(x); }

// ---- pf (f32 param) sublayout ----
#define PF_EMBA 0
#define PF_EMBB 64
#define PF_WAB  128
#define PF_BAB  8320
#define PF_WBA  8448
#define PF_BBA  16640
#define PF_BTA  16768
#define PF_BTB  16896
#define PF_TOT  17024

// ---- ws layout (4-byte units) ----
#define WS_HIST   0
#define WS_CUR    (4*NN)
#define WS_RS     (6*NN)
#define WS_OFFAB  (10*NN)
#define WS_OFFBA  (11*NN + 16)
#define WS_PF     (12*NN + 32)
#define WS_V      (WS_PF + PF_TOT)
#define WS_FLAG   (WS_V + 128)
#define WS_CSRAB  (13*NN)          // 1,300,000 > WS_FLAG+pad
#define WS_CSRBA  (WS_CSRAB + NE)
#define WS_HS     (WS_CSRBA + NE)  // bf16 region (2*ND bf16)

// 64-lane LayerNorm
__device__ __forceinline__ float wave_ln(float x, float beta){
  float s = x, s2 = x*x;
  #pragma unroll
  for (int off = 32; off >= 1; off >>= 1){
    s  += __shfl_xor(s,  off);
    s2 += __shfl_xor(s2, off);
  }
  float mu  = s  * (1.0f/DD);
  float var = s2 * (1.0f/DD) - mu*mu;
  return (x - mu) * rsqrtf(var + EPSLN) + beta;
}

// dtype sniff on W_ab bits (bf16 exponents cluster in [110,130]; f32-as-u16 doesn't)
__global__ void k_detect(const unsigned short* __restrict__ w, int* __restrict__ flag){
  int lane = threadIdx.x;
  int bad = 0;
  for (int i = lane; i < 4096; i += 64){
    int e = (w[i] >> 7) & 0xFF;
    if (e < 110 || e > 130) bad++;
  }
  #pragma unroll
  for (int off = 32; off >= 1; off >>= 1) bad += __shfl_xor(bad, off);
  if (lane == 0) *flag = (bad > 500) ? 1 : 0;   // 1 = f32, 0 = bf16
}

__global__ void k_convert(const void* embA, const void* embB, const void* Wab, const void* bab,
                          const void* Wba, const void* bba, const void* betaA, const void* betaB,
                          const int* __restrict__ flag, float* __restrict__ pf){
  int i = blockIdx.x*blockDim.x + threadIdx.x;
  if (i >= PF_TOT) return;
  int f32 = *flag;
  const void* src; int j;
  if      (i < PF_EMBB) { src=embA;  j=i; }
  else if (i < PF_WAB)  { src=embB;  j=i-PF_EMBB; }
  else if (i < PF_BAB)  { src=Wab;   j=i-PF_WAB; }
  else if (i < PF_WBA)  { src=bab;   j=i-PF_BAB; }
  else if (i < PF_BBA)  { src=Wba;   j=i-PF_WBA; }
  else if (i < PF_BTA)  { src=bba;   j=i-PF_BBA; }
  else if (i < PF_BTB)  { src=betaA; j=i-PF_BTA; }
  else                  { src=betaB; j=i-PF_BTB; }
  pf[i] = f32 ? ((const float*)src)[j] : b2f(((const bf16*)src)[j]);
}

// hist: [0,N) cnt(sab)  [N,2N) cnt(dab)  [2N,3N) cnt(sba)  [3N,4N) cnt(dba)
__global__ void k_hist(const int* __restrict__ sab, const int* __restrict__ dab,
                       const int* __restrict__ sba, const int* __restrict__ dba,
                       int* __restrict__ hist){
  int e = blockIdx.x*blockDim.x + threadIdx.x;
  if (e >= NE) return;
  atomicAdd(&hist[sab[e]], 1);
  atomicAdd(&hist[NN + dab[e]], 1);
  atomicAdd(&hist[2*NN + sba[e]], 1);
  atomicAdd(&hist[3*NN + dba[e]], 1);
}

__global__ void k_rs(const int* __restrict__ hist, float* __restrict__ rs){
  int i = blockIdx.x*blockDim.x + threadIdx.x;
  if (i >= 4*NN) return;
  rs[i] = rsqrtf((float)max(hist[i], 1));
}

// exclusive scan of in-degree counts -> CSR row offsets. block 0: AB (dab), block 1: BA (dba)
__global__ void k_scan(const int* __restrict__ hist, int* __restrict__ offAB, int* __restrict__ offBA){
  __shared__ int lds[1024];
  __shared__ int sbase;
  const int* c = (blockIdx.x == 0) ? (hist + NN) : (hist + 3*NN);
  int* o       = (blockIdx.x == 0) ? offAB : offBA;
  if (threadIdx.x == 0) sbase = 0;
  __syncthreads();
  for (int start = 0; start < NN; start += 1024){
    int i = start + (int)threadIdx.x;
    int x = (i < NN) ? c[i] : 0;
    lds[threadIdx.x] = x;
    __syncthreads();
    for (int d = 1; d < 1024; d <<= 1){
      int t = (threadIdx.x >= (unsigned)d) ? lds[threadIdx.x - d] : 0;
      __syncthreads();
      lds[threadIdx.x] += t;
      __syncthreads();
    }
    int incl = lds[threadIdx.x];
    int b = sbase;
    __syncthreads();
    if (i < NN) o[i] = b + incl - x;
    if (threadIdx.x == 1023) sbase = b + lds[1023];
    __syncthreads();
  }
  if (threadIdx.x == 0) o[NN] = sbase;
}

// scatter edge srcs into per-dst buckets via atomic cursors
__global__ void k_bucket(const int* __restrict__ sab, const int* __restrict__ dab,
                         const int* __restrict__ sba, const int* __restrict__ dba,
                         const int* __restrict__ offAB, const int* __restrict__ offBA,
                         int* __restrict__ cur, int* __restrict__ csrAB, int* __restrict__ csrBA){
  int e = blockIdx.x*blockDim.x + threadIdx.x;
  if (e >= 2*NE) return;
  if (e < NE){
    int d = dab[e];
    int pos = atomicAdd(&cur[d], 1);
    csrAB[offAB[d] + pos] = sab[e];
  } else {
    int ee = e - NE;
    int d = dba[ee];
    int pos = atomicAdd(&cur[NN + d], 1);
    csrBA[offBA[d] + pos] = sba[ee];
  }
}

// vAB = embA @ Wab[0], vBA = embB @ Wba[0]
__global__ void k_matvec(const float* __restrict__ pf, float* __restrict__ v){
  int t = threadIdx.x;           // 128 threads
  int d = t & (DD-1);
  const float* emb = pf + ((t < DD) ? PF_EMBA : PF_EMBB);
  const float* W   = pf + ((t < DD) ? PF_WAB  : PF_WBA);
  float acc = 0.f;
  for (int k = 0; k < DD; k++) acc += emb[k] * W[k*DD + d];
  v[(t < DD) ? d : (DD + d)] = acc;
}

// layer-0: wave per node (CSR gather of scalar coefs).
// writes h -> d_out (flag dtype) and hs = bf16(h * rs_out) -> ws
__global__ void k_layer0(const int* __restrict__ csrAB, const int* __restrict__ csrBA,
                         const int* __restrict__ offAB, const int* __restrict__ offBA,
                         const float* __restrict__ rs, const float* __restrict__ v,
                         const float* __restrict__ pf, const int* __restrict__ flag,
                         void* __restrict__ out, bf16* __restrict__ hsA, bf16* __restrict__ hsB){
  int w = (blockIdx.x*blockDim.x + threadIdx.x) >> 6;
  int lane = threadIdx.x & 63;
  if (w >= 2*NN) return;
  int f32 = *flag;
  bool isA = (w < NN);
  int n = isA ? w : (w - NN);
  const int* csr; const int* off; int rsbase;
  float vd, bias, beta, e0, rin;
  if (isA){   // outA over ba edges
    csr = csrBA; off = offBA; rsbase = 2*NN; rin = rs[3*NN + n];
    vd = v[DD + lane]; bias = pf[PF_BBA + lane]; beta = pf[PF_BTA + lane]; e0 = pf[PF_EMBA + lane];
  } else {    // outB over ab edges
    csr = csrAB; off = offAB; rsbase = 0;    rin = rs[NN + n];
    vd = v[lane];      bias = pf[PF_BAB + lane]; beta = pf[PF_BTB + lane]; e0 = pf[PF_EMBB + lane];
  }
  int o0 = off[n], o1 = off[n+1];
  float c = 0.f;
  for (int t = o0 + lane; t < o1; t += 64) c += rs[rsbase + csr[t]];
  #pragma unroll
  for (int off2 = 32; off2 >= 1; off2 >>= 1) c += __shfl_xor(c, off2);
  float ov = fmaxf(c * rin * vd + bias, 0.f);
  float res = wave_ln(e0 + ov, beta);
  size_t idx = (size_t)w*DD + lane;
  if (f32) ((float*)out)[idx] = res;
  else     ((bf16*)out)[idx] = __float2bfloat16(res);
  float rscale = isA ? rs[n] : rs[2*NN + n];   // out-degree scale as SOURCE
  (isA ? hsA : hsB)[(size_t)n*DD + lane] = __float2bfloat16(res * rscale);
}

// layer-1 fused gather + matvec + LN. Block = 4 waves = 4 nodes (exact grid).
// lane = feature (verified round-3 formulation); 8-edge manual unroll for MLP:
// 8 independent 2B row-loads in flight instead of 1.
__global__ __launch_bounds__(256) void k_gather_l1(
    const int* __restrict__ csr, const int* __restrict__ off,
    const bf16* __restrict__ hs, const float* __restrict__ rs_in,
    const float* __restrict__ W, const float* __restrict__ bias_,
    const float* __restrict__ beta_, const int* __restrict__ flag,
    void* __restrict__ out, size_t base){
  int lane = threadIdx.x & 63;
  int wid  = threadIdx.x >> 6;
  int n = blockIdx.x*4 + wid;          // grid = 25000 blocks -> n < 100000 always
  int f32 = *flag;
  float Wcol[DD];
  #pragma unroll
  for (int k = 0; k < DD; k++) Wcol[k] = W[k*DD + lane];
  float bs = bias_[lane];
  float bt = beta_[lane];
  int o0 = off[n], o1 = off[n+1];
  float acc = 0.f;
  int t = o0;
  for (; t + 8 <= o1; t += 8){         // wave-uniform t -> scalar csr loads
    int s0 = csr[t],   s1 = csr[t+1], s2 = csr[t+2], s3 = csr[t+3];
    int s4 = csr[t+4], s5 = csr[t+5], s6 = csr[t+6], s7 = csr[t+7];
    float v0 = b2f(hs[(size_t)s0*DD + lane]);
    float v1 = b2f(hs[(size_t)s1*DD + lane]);
    float v2 = b2f(hs[(size_t)s2*DD + lane]);
    float v3 = b2f(hs[(size_t)s3*DD + lane]);
    float v4 = b2f(hs[(size_t)s4*DD + lane]);
    float v5 = b2f(hs[(size_t)s5*DD + lane]);
    float v6 = b2f(hs[(size_t)s6*DD + lane]);
    float v7 = b2f(hs[(size_t)s7*DD + lane]);
    acc += ((v0 + v1) + (v2 + v3)) + ((v4 + v5) + (v6 + v7));
  }
  for (; t < o1; t++){
    int s = csr[t];
    acc += b2f(hs[(size_t)s*DD + lane]);
  }
  __shared__ __align__(16) float srow[4][DD];
  srow[wid][lane] = acc;
  __syncthreads();                     // block-uniform point
  const float4* ar = (const float4*)srow[wid];
  float o = 0.f;
  #pragma unroll
  for (int k4 = 0; k4 < DD/4; k4++){
    float4 a4 = ar[k4];                // wave-uniform LDS broadcast
    o += a4.x*Wcol[4*k4] + a4.y*Wcol[4*k4+1] + a4.z*Wcol[4*k4+2] + a4.w*Wcol[4*k4+3];
  }
  o = fmaxf(o * rs_in[n] + bs, 0.f);
  size_t idx = base + (size_t)n*DD + lane;
  float hv = f32 ? ((const float*)out)[idx] : b2f(((const bf16*)out)[idx]);
  float res = wave_ln(hv + o, bt);
  if (f32) ((float*)out)[idx] = res;
  else     ((bf16*)out)[idx] = __float2bfloat16(res);
}

extern "C" void kernel_launch(void* const* d_in, const int* in_sizes, int n_in,
                              void* d_out, int out_size, void* d_ws, size_t ws_size,
                              hipStream_t stream){
  const int* sab = (const int*)d_in[0];
  const int* dab = (const int*)d_in[1];
  const int* sba = (const int*)d_in[2];
  const int* dba = (const int*)d_in[3];

  int*   wsi   = (int*)d_ws;
  float* wsf   = (float*)d_ws;
  int*   hist  = wsi + WS_HIST;
  int*   cur   = wsi + WS_CUR;
  float* rs    = wsf + WS_RS;
  int*   offAB = wsi + WS_OFFAB;
  int*   offBA = wsi + WS_OFFBA;
  float* pf    = wsf + WS_PF;
  float* v     = wsf + WS_V;
  int*   flag  = wsi + WS_FLAG;
  int*   csrAB = wsi + WS_CSRAB;
  int*   csrBA = wsi + WS_CSRBA;
  bf16*  hsA   = (bf16*)(wsi + WS_HS);
  bf16*  hsB   = hsA + ND;

  // zero hist[4N] + cur[2N] (contiguous)
  hipMemsetAsync(d_ws, 0, (size_t)(6*NN)*sizeof(int), stream);

  k_detect <<<1, 64, 0, stream>>>((const unsigned short*)d_in[6], flag);
  k_convert<<<(PF_TOT+255)/256, 256, 0, stream>>>(d_in[4], d_in[5], d_in[6], d_in[7],
                                                  d_in[8], d_in[9], d_in[10], d_in[11],
                                                  flag, pf);
  k_hist   <<<(NE+255)/256, 256, 0, stream>>>(sab, dab, sba, dba, hist);
  k_rs     <<<(4*NN+255)/256, 256, 0, stream>>>(hist, rs);
  k_scan   <<<2, 1024, 0, stream>>>(hist, offAB, offBA);
  k_bucket <<<(2*NE+255)/256, 256, 0, stream>>>(sab, dab, sba, dba, offAB, offBA,
                                                cur, csrAB, csrBA);
  k_matvec <<<1, 128, 0, stream>>>(pf, v);
  k_layer0 <<<(2*NN)/4, 256, 0, stream>>>(csrAB, csrBA, offAB, offBA, rs, v, pf, flag,
                                          d_out, hsA, hsB);
  // A half: in-edges = ba relation, sources are B nodes
  k_gather_l1<<<NN/4, 256, 0, stream>>>(csrBA, offBA, hsB, rs + 3*NN,
                                        pf + PF_WBA + DD*DD, pf + PF_BBA + DD,
                                        pf + PF_BTA + DD, flag, d_out, 0);
  // B half: in-edges = ab relation, sources are A nodes
  k_gather_l1<<<NN/4, 256, 0, stream>>>(csrAB, offAB, hsA, rs + NN,
                                        pf + PF_WAB + DD*DD, pf + PF_BAB + DD,
                                        pf + PF_BTB + DD, flag, d_out, (size_t)ND);
}

// Round 6
// 978.746 us; speedup vs baseline: 1.5689x; 1.2058x over previous
//
#include <hip/hip_runtime.h>
#include <hip/hip_bf16.h>

#define NN 100000
#define DD 64
#define NE 1600000
#define ND (NN*DD)
#define EPSLN 1e-3f

typedef __hip_bfloat16 bf16;
__device__ __forceinline__ float b2f(bf16 x){ return __bfloat162float(x); }

// ---- pf (f32 param) sublayout ----
#define PF_EMBA 0
#define PF_EMBB 64
#define PF_WAB  128
#define PF_BAB  8320
#define PF_WBA  8448
#define PF_BBA  16640
#define PF_BTA  16768
#define PF_BTB  16896
#define PF_TOT  17024

// ---- ws layout (4-byte units) ----
#define WS_HIST   0
#define WS_CUR    (4*NN)
#define WS_RS     (6*NN)
#define WS_OFFAB  (10*NN)
#define WS_OFFBA  (11*NN + 16)
#define WS_PF     (12*NN + 32)
#define WS_V      (WS_PF + PF_TOT)
#define WS_FLAG   (WS_V + 128)
#define WS_BSUM   (WS_FLAG + 16)   // 196 ints
#define WS_CSRAB  (13*NN)          // 1,300,000 > WS_BSUM+196 (~1,217,396)
#define WS_CSRBA  (WS_CSRAB + NE)
#define WS_HS     (WS_CSRBA + NE)  // bf16 region (2*ND bf16)

// 64-lane LayerNorm
__device__ __forceinline__ float wave_ln(float x, float beta){
  float s = x, s2 = x*x;
  #pragma unroll
  for (int off = 32; off >= 1; off >>= 1){
    s  += __shfl_xor(s,  off);
    s2 += __shfl_xor(s2, off);
  }
  float mu  = s  * (1.0f/DD);
  float var = s2 * (1.0f/DD) - mu*mu;
  return (x - mu) * rsqrtf(var + EPSLN) + beta;
}

// dtype sniff on W_ab bits (bf16 exponents cluster in [110,130]; f32-as-u16 doesn't)
__global__ void k_detect(const unsigned short* __restrict__ w, int* __restrict__ flag){
  int lane = threadIdx.x;
  int bad = 0;
  for (int i = lane; i < 4096; i += 64){
    int e = (w[i] >> 7) & 0xFF;
    if (e < 110 || e > 130) bad++;
  }
  #pragma unroll
  for (int off = 32; off >= 1; off >>= 1) bad += __shfl_xor(bad, off);
  if (lane == 0) *flag = (bad > 500) ? 1 : 0;   // 1 = f32, 0 = bf16
}

__global__ void k_convert(const void* embA, const void* embB, const void* Wab, const void* bab,
                          const void* Wba, const void* bba, const void* betaA, const void* betaB,
                          const int* __restrict__ flag, float* __restrict__ pf){
  int i = blockIdx.x*blockDim.x + threadIdx.x;
  if (i >= PF_TOT) return;
  int f32 = *flag;
  const void* src; int j;
  if      (i < PF_EMBB) { src=embA;  j=i; }
  else if (i < PF_WAB)  { src=embB;  j=i-PF_EMBB; }
  else if (i < PF_BAB)  { src=Wab;   j=i-PF_WAB; }
  else if (i < PF_WBA)  { src=bab;   j=i-PF_BAB; }
  else if (i < PF_BBA)  { src=Wba;   j=i-PF_WBA; }
  else if (i < PF_BTA)  { src=bba;   j=i-PF_BBA; }
  else if (i < PF_BTB)  { src=betaA; j=i-PF_BTA; }
  else                  { src=betaB; j=i-PF_BTB; }
  pf[i] = f32 ? ((const float*)src)[j] : b2f(((const bf16*)src)[j]);
}

// hist: [0,N) cnt(sab)  [N,2N) cnt(dab)  [2N,3N) cnt(sba)  [3N,4N) cnt(dba)
// 4 edges per thread via int4 (NE % 4 == 0)
__global__ void k_hist(const int* __restrict__ sab, const int* __restrict__ dab,
                       const int* __restrict__ sba, const int* __restrict__ dba,
                       int* __restrict__ hist){
  int t = blockIdx.x*blockDim.x + threadIdx.x;
  if (t >= NE/4) return;
  int4 a = ((const int4*)sab)[t];
  int4 b = ((const int4*)dab)[t];
  int4 c = ((const int4*)sba)[t];
  int4 d = ((const int4*)dba)[t];
  atomicAdd(&hist[a.x],1); atomicAdd(&hist[a.y],1); atomicAdd(&hist[a.z],1); atomicAdd(&hist[a.w],1);
  atomicAdd(&hist[NN+b.x],1); atomicAdd(&hist[NN+b.y],1); atomicAdd(&hist[NN+b.z],1); atomicAdd(&hist[NN+b.w],1);
  atomicAdd(&hist[2*NN+c.x],1); atomicAdd(&hist[2*NN+c.y],1); atomicAdd(&hist[2*NN+c.z],1); atomicAdd(&hist[2*NN+c.w],1);
  atomicAdd(&hist[3*NN+d.x],1); atomicAdd(&hist[3*NN+d.y],1); atomicAdd(&hist[3*NN+d.z],1); atomicAdd(&hist[3*NN+d.w],1);
}

__global__ void k_rs(const int* __restrict__ hist, float* __restrict__ rs){
  int i = blockIdx.x*blockDim.x + threadIdx.x;
  if (i >= 4*NN) return;
  rs[i] = rsqrtf((float)max(hist[i], 1));
}

// ---- parallel exclusive scan of the two in-degree histograms ----
// scan1: 196 blocks (rel = blk/98), each scans 1024 elems in LDS, writes
// per-block exclusive values + block sum
__global__ void k_scan1(const int* __restrict__ hist, int* __restrict__ offAB,
                        int* __restrict__ offBA, int* __restrict__ bsum){
  __shared__ int lds[1024];
  int rel = blockIdx.x / 98, b = blockIdx.x % 98;
  const int* c = hist + (rel ? 3*NN : NN);
  int* o       = rel ? offBA : offAB;
  int i = b*1024 + (int)threadIdx.x;
  int x = (i < NN) ? c[i] : 0;
  lds[threadIdx.x] = x;
  __syncthreads();
  for (int d = 1; d < 1024; d <<= 1){
    int t = (threadIdx.x >= (unsigned)d) ? lds[threadIdx.x - d] : 0;
    __syncthreads();
    lds[threadIdx.x] += t;
    __syncthreads();
  }
  if (i < NN) o[i] = lds[threadIdx.x] - x;          // exclusive within block
  if (threadIdx.x == 1023) bsum[rel*98 + b] = lds[1023];
}

// scan2: one block; exclusive scan of the 98 block sums per relation
__global__ void k_scan2(int* __restrict__ bsum){
  __shared__ int lds[256];
  int rel = threadIdx.x >> 7;
  int j = threadIdx.x & 127;
  int x = (j < 98) ? bsum[rel*98 + j] : 0;
  lds[threadIdx.x] = x;
  __syncthreads();
  for (int d = 1; d < 128; d <<= 1){
    int t = (j >= d) ? lds[threadIdx.x - d] : 0;
    __syncthreads();
    lds[threadIdx.x] += t;
    __syncthreads();
  }
  if (j < 98) bsum[rel*98 + j] = lds[threadIdx.x] - x;   // exclusive
}

// scan3: add block offsets; set off[NN] = NE
__global__ void k_scan3(int* __restrict__ offAB, int* __restrict__ offBA,
                        const int* __restrict__ bsum){
  int i = blockIdx.x*blockDim.x + threadIdx.x;
  if (i >= 2*NN) return;
  int rel = (i < NN) ? 0 : 1;
  int n = i - rel*NN;
  int* o = rel ? offBA : offAB;
  o[n] += bsum[rel*98 + (n >> 10)];
  if (i == 0)  offAB[NN] = NE;
  if (i == NN) offBA[NN] = NE;
}

// scatter edge srcs into per-dst buckets via atomic cursors; 4 edges of each
// relation per thread via int4 (bucket order is irrelevant: only summed over)
__global__ void k_bucket(const int* __restrict__ sab, const int* __restrict__ dab,
                         const int* __restrict__ sba, const int* __restrict__ dba,
                         const int* __restrict__ offAB, const int* __restrict__ offBA,
                         int* __restrict__ cur, int* __restrict__ csrAB, int* __restrict__ csrBA){
  int t = blockIdx.x*blockDim.x + threadIdx.x;
  if (t >= NE/4) return;
  int4 s = ((const int4*)sab)[t];
  int4 d = ((const int4*)dab)[t];
  int4 u = ((const int4*)sba)[t];
  int4 w = ((const int4*)dba)[t];
  int p;
  p = atomicAdd(&cur[d.x], 1); csrAB[offAB[d.x] + p] = s.x;
  p = atomicAdd(&cur[d.y], 1); csrAB[offAB[d.y] + p] = s.y;
  p = atomicAdd(&cur[d.z], 1); csrAB[offAB[d.z] + p] = s.z;
  p = atomicAdd(&cur[d.w], 1); csrAB[offAB[d.w] + p] = s.w;
  p = atomicAdd(&cur[NN + w.x], 1); csrBA[offBA[w.x] + p] = u.x;
  p = atomicAdd(&cur[NN + w.y], 1); csrBA[offBA[w.y] + p] = u.y;
  p = atomicAdd(&cur[NN + w.z], 1); csrBA[offBA[w.z] + p] = u.z;
  p = atomicAdd(&cur[NN + w.w], 1); csrBA[offBA[w.w] + p] = u.w;
}

// vAB = embA @ Wab[0], vBA = embB @ Wba[0]
__global__ void k_matvec(const float* __restrict__ pf, float* __restrict__ v){
  int t = threadIdx.x;           // 128 threads
  int d = t & (DD-1);
  const float* emb = pf + ((t < DD) ? PF_EMBA : PF_EMBB);
  const float* W   = pf + ((t < DD) ? PF_WAB  : PF_WBA);
  float acc = 0.f;
  for (int k = 0; k < DD; k++) acc += emb[k] * W[k*DD + d];
  v[(t < DD) ? d : (DD + d)] = acc;
}

// layer-0: wave per node (CSR gather of scalar coefs).
// writes h -> d_out (flag dtype) and hs = bf16(h * rs_out) -> ws
__global__ void k_layer0(const int* __restrict__ csrAB, const int* __restrict__ csrBA,
                         const int* __restrict__ offAB, const int* __restrict__ offBA,
                         const float* __restrict__ rs, const float* __restrict__ v,
                         const float* __restrict__ pf, const int* __restrict__ flag,
                         void* __restrict__ out, bf16* __restrict__ hsA, bf16* __restrict__ hsB){
  int w = (blockIdx.x*blockDim.x + threadIdx.x) >> 6;
  int lane = threadIdx.x & 63;
  if (w >= 2*NN) return;
  int f32 = *flag;
  bool isA = (w < NN);
  int n = isA ? w : (w - NN);
  const int* csr; const int* off; int rsbase;
  float vd, bias, beta, e0, rin;
  if (isA){   // outA over ba edges
    csr = csrBA; off = offBA; rsbase = 2*NN; rin = rs[3*NN + n];
    vd = v[DD + lane]; bias = pf[PF_BBA + lane]; beta = pf[PF_BTA + lane]; e0 = pf[PF_EMBA + lane];
  } else {    // outB over ab edges
    csr = csrAB; off = offAB; rsbase = 0;    rin = rs[NN + n];
    vd = v[lane];      bias = pf[PF_BAB + lane]; beta = pf[PF_BTB + lane]; e0 = pf[PF_EMBB + lane];
  }
  int o0 = off[n], o1 = off[n+1];
  float c = 0.f;
  for (int t = o0 + lane; t < o1; t += 64) c += rs[rsbase + csr[t]];
  #pragma unroll
  for (int off2 = 32; off2 >= 1; off2 >>= 1) c += __shfl_xor(c, off2);
  float ov = fmaxf(c * rin * vd + bias, 0.f);
  float res = wave_ln(e0 + ov, beta);
  size_t idx = (size_t)w*DD + lane;
  if (f32) ((float*)out)[idx] = res;
  else     ((bf16*)out)[idx] = __float2bfloat16(res);
  float rscale = isA ? rs[n] : rs[2*NN + n];   // out-degree scale as SOURCE
  (isA ? hsA : hsB)[(size_t)n*DD + lane] = __float2bfloat16(res * rscale);
}

// layer-1 fused gather + matvec + LN, BOTH halves in one dispatch.
// Inner loop identical to the round-5 verified body (8-edge unroll, lane=feature).
// NN % 4 == 0 -> every block is uniformly A or B.
__global__ __launch_bounds__(256) void k_gather_l1(
    const int* __restrict__ csrAB, const int* __restrict__ csrBA,
    const int* __restrict__ offAB, const int* __restrict__ offBA,
    const bf16* __restrict__ hsA, const bf16* __restrict__ hsB,
    const float* __restrict__ rs, const float* __restrict__ pf,
    const int* __restrict__ flag, void* __restrict__ out){
  int lane = threadIdx.x & 63;
  int wid  = threadIdx.x >> 6;
  int w = blockIdx.x*4 + wid;          // [0, 2N) exact grid
  int f32 = *flag;
  bool isA = (w < NN);
  int n = isA ? w : (w - NN);
  const int* csr  = isA ? csrBA : csrAB;
  const int* off  = isA ? offBA : offAB;
  const bf16* hs  = isA ? hsB  : hsA;
  const float* W  = pf + (isA ? PF_WBA : PF_WAB) + DD*DD;
  float bs  = pf[(isA ? PF_BBA : PF_BAB) + DD + lane];
  float bt  = pf[(isA ? PF_BTA : PF_BTB) + DD + lane];
  float rin = isA ? rs[3*NN + n] : rs[NN + n];

  float Wcol[DD];
  #pragma unroll
  for (int k = 0; k < DD; k++) Wcol[k] = W[k*DD + lane];

  int o0 = off[n], o1 = off[n+1];
  float acc = 0.f;
  int t = o0;
  for (; t + 8 <= o1; t += 8){         // wave-uniform t -> scalar csr loads
    int s0 = csr[t],   s1 = csr[t+1], s2 = csr[t+2], s3 = csr[t+3];
    int s4 = csr[t+4], s5 = csr[t+5], s6 = csr[t+6], s7 = csr[t+7];
    float v0 = b2f(hs[(size_t)s0*DD + lane]);
    float v1 = b2f(hs[(size_t)s1*DD + lane]);
    float v2 = b2f(hs[(size_t)s2*DD + lane]);
    float v3 = b2f(hs[(size_t)s3*DD + lane]);
    float v4 = b2f(hs[(size_t)s4*DD + lane]);
    float v5 = b2f(hs[(size_t)s5*DD + lane]);
    float v6 = b2f(hs[(size_t)s6*DD + lane]);
    float v7 = b2f(hs[(size_t)s7*DD + lane]);
    acc += ((v0 + v1) + (v2 + v3)) + ((v4 + v5) + (v6 + v7));
  }
  for (; t < o1; t++){
    int s = csr[t];
    acc += b2f(hs[(size_t)s*DD + lane]);
  }
  __shared__ __align__(16) float srow[4][DD];
  srow[wid][lane] = acc;
  __syncthreads();                     // block-uniform point
  const float4* ar = (const float4*)srow[wid];
  float o = 0.f;
  #pragma unroll
  for (int k4 = 0; k4 < DD/4; k4++){
    float4 a4 = ar[k4];                // wave-uniform LDS broadcast
    o += a4.x*Wcol[4*k4] + a4.y*Wcol[4*k4+1] + a4.z*Wcol[4*k4+2] + a4.w*Wcol[4*k4+3];
  }
  o = fmaxf(o * rin + bs, 0.f);
  size_t idx = (size_t)w*DD + lane;    // A half then B half, same as h layout
  float hv = f32 ? ((const float*)out)[idx] : b2f(((const bf16*)out)[idx]);
  float res = wave_ln(hv + o, bt);
  if (f32) ((float*)out)[idx] = res;
  else     ((bf16*)out)[idx] = __float2bfloat16(res);
}

extern "C" void kernel_launch(void* const* d_in, const int* in_sizes, int n_in,
                              void* d_out, int out_size, void* d_ws, size_t ws_size,
                              hipStream_t stream){
  const int* sab = (const int*)d_in[0];
  const int* dab = (const int*)d_in[1];
  const int* sba = (const int*)d_in[2];
  const int* dba = (const int*)d_in[3];

  int*   wsi   = (int*)d_ws;
  float* wsf   = (float*)d_ws;
  int*   hist  = wsi + WS_HIST;
  int*   cur   = wsi + WS_CUR;
  float* rs    = wsf + WS_RS;
  int*   offAB = wsi + WS_OFFAB;
  int*   offBA = wsi + WS_OFFBA;
  float* pf    = wsf + WS_PF;
  float* v     = wsf + WS_V;
  int*   flag  = wsi + WS_FLAG;
  int*   bsum  = wsi + WS_BSUM;
  int*   csrAB = wsi + WS_CSRAB;
  int*   csrBA = wsi + WS_CSRBA;
  bf16*  hsA   = (bf16*)(wsi + WS_HS);
  bf16*  hsB   = hsA + ND;

  // zero hist[4N] + cur[2N] (contiguous)
  hipMemsetAsync(d_ws, 0, (size_t)(6*NN)*sizeof(int), stream);

  k_detect <<<1, 64, 0, stream>>>((const unsigned short*)d_in[6], flag);
  k_convert<<<(PF_TOT+255)/256, 256, 0, stream>>>(d_in[4], d_in[5], d_in[6], d_in[7],
                                                  d_in[8], d_in[9], d_in[10], d_in[11],
                                                  flag, pf);
  k_hist   <<<(NE/4+255)/256, 256, 0, stream>>>(sab, dab, sba, dba, hist);
  k_rs     <<<(4*NN+255)/256, 256, 0, stream>>>(hist, rs);
  k_scan1  <<<196, 1024, 0, stream>>>(hist, offAB, offBA, bsum);
  k_scan2  <<<1, 256, 0, stream>>>(bsum);
  k_scan3  <<<(2*NN+255)/256, 256, 0, stream>>>(offAB, offBA, bsum);
  k_bucket <<<(NE/4+255)/256, 256, 0, stream>>>(sab, dab, sba, dba, offAB, offBA,
                                                cur, csrAB, csrBA);
  k_matvec <<<1, 128, 0, stream>>>(pf, v);
  k_layer0 <<<(2*NN)/4, 256, 0, stream>>>(csrAB, csrBA, offAB, offBA, rs, v, pf, flag,
                                          d_out, hsA, hsB);
  k_gather_l1<<<(2*NN)/4, 256, 0, stream>>>(csrAB, csrBA, offAB, offBA, hsA, hsB,
                                            rs, pf, flag, d_out);
}